// Round 1
// baseline (1485.564 us; speedup 1.0000x reference)
//
#include <hip/hip_runtime.h>

#define D 64

// ---------------------------------------------------------------------------
// Stage 1: edge scatter-add.  agg[row] += F[col] * val for each edge.
// One edge per 16-lane group; each lane handles a float4 (16B) slice.
// unsafeAtomicAdd -> global_atomic_add_f32 (HW fadd at L2, no CAS loop).
// ---------------------------------------------------------------------------
__global__ void agg_kernel(const float* __restrict__ feat,
                           const int* __restrict__ erows,
                           const int* __restrict__ ecols,
                           const float* __restrict__ evals,
                           float* __restrict__ agg,
                           int n_edges) {
    int gid    = blockIdx.x * blockDim.x + threadIdx.x;
    int group  = gid >> 4;        // edge slot
    int lane4  = gid & 15;        // which float4 of the 64-float row
    int stride = (gridDim.x * blockDim.x) >> 4;

    for (int e = group; e < n_edges; e += stride) {
        int   r = erows[e];
        int   c = ecols[e];
        float v = evals[e];
        const float4 f =
            *reinterpret_cast<const float4*>(feat + (size_t)c * D + lane4 * 4);
        float* dst = agg + (size_t)r * D + lane4 * 4;
        unsafeAtomicAdd(dst + 0, f.x * v);
        unsafeAtomicAdd(dst + 1, f.y * v);
        unsafeAtomicAdd(dst + 2, f.z * v);
        unsafeAtomicAdd(dst + 3, f.w * v);
    }
}

// ---------------------------------------------------------------------------
// Stage 2: out = relu(agg @ W).  W (64x64 f32 = 16KB) staged in LDS.
// 256 threads = 4 row-groups of 64 threads; thread j of a group computes
// output column j of its row.  Row staged in LDS first -> in-place safe
// (agg may alias out when ws is too small).
// ---------------------------------------------------------------------------
__global__ void __launch_bounds__(256)
proj_kernel(const float* __restrict__ agg,
            const float* __restrict__ W,
            float* __restrict__ out,
            int n_rows) {
    __shared__ float sW[D * D];     // 16 KB
    __shared__ float srow[4][D];    // 1 KB

    for (int i = threadIdx.x; i < D * D; i += 256)
        sW[i] = W[i];
    __syncthreads();

    const int rg = threadIdx.x >> 6;   // row group 0..3
    const int j  = threadIdx.x & 63;   // output column

    for (int row0 = blockIdx.x * 4; row0 < n_rows; row0 += gridDim.x * 4) {
        int r = row0 + rg;
        float v = (r < n_rows) ? agg[(size_t)r * D + j] : 0.0f;
        srow[rg][j] = v;
        __syncthreads();

        float acc = 0.0f;
#pragma unroll
        for (int k = 0; k < D; ++k)
            acc = fmaf(srow[rg][k], sW[k * D + j], acc);

        if (r < n_rows)
            out[(size_t)r * D + j] = fmaxf(acc, 0.0f);
        __syncthreads();   // before srow is overwritten next iter
    }
}

extern "C" void kernel_launch(void* const* d_in, const int* in_sizes, int n_in,
                              void* d_out, int out_size, void* d_ws, size_t ws_size,
                              hipStream_t stream) {
    const float* feat  = (const float*)d_in[0];
    const int*   erows = (const int*)  d_in[1];
    const int*   ecols = (const int*)  d_in[2];
    const float* evals = (const float*)d_in[3];
    const float* W     = (const float*)d_in[4];
    float*       out   = (float*)d_out;

    const int n_edges = in_sizes[1];
    const int n_nodes = in_sizes[0] / D;

    const size_t agg_bytes = (size_t)n_nodes * D * sizeof(float);
    float* agg = (ws_size >= agg_bytes) ? (float*)d_ws : out;

    hipMemsetAsync(agg, 0, agg_bytes, stream);

    const int blk = 256;
    agg_kernel<<<2048, blk, 0, stream>>>(feat, erows, ecols, evals, agg, n_edges);
    proj_kernel<<<2048, blk, 0, stream>>>(agg, W, out, n_nodes);
}

// Round 3
// 397.144 us; speedup vs baseline: 3.7406x; 3.7406x over previous
//
#include <hip/hip_runtime.h>

#define D 64

// ===========================================================================
// Fast path: build CSR on device, then fused gather+aggregate+project.
// ws layout (all offsets 256B-aligned):
//   rowStart : (N+1) int   — CSR row offsets (rowStart[N] = E)
//   cur      : N int       — histogram, then scatter cursor (same buffer)
//   bs       : nblk int    — per-block sums for the scan
//   pairs    : E int2      — (col, float_bits(val)) sorted by row
// ===========================================================================

// ---- K2: histogram of edge rows into cur[] (int atomics, L2-resident) ----
__global__ void hist_kernel(const int* __restrict__ erows, int* __restrict__ cur,
                            int n_edges) {
    int i = blockIdx.x * blockDim.x + threadIdx.x;
    int stride = gridDim.x * blockDim.x;
    for (int e = i; e < n_edges; e += stride)
        atomicAdd(&cur[erows[e]], 1);
}

// ---- K3a: per-256-block sums ----
__global__ void __launch_bounds__(256)
scan_block_reduce(const int* __restrict__ cnt, int* __restrict__ bs, int n) {
    __shared__ int s[256];
    int i = blockIdx.x * 256 + threadIdx.x;
    s[threadIdx.x] = (i < n) ? cnt[i] : 0;
    __syncthreads();
    for (int off = 128; off > 0; off >>= 1) {
        if (threadIdx.x < (unsigned)off) s[threadIdx.x] += s[threadIdx.x + off];
        __syncthreads();
    }
    if (threadIdx.x == 0) bs[blockIdx.x] = s[0];
}

// ---- K3b: exclusive scan of block sums (single block, nblk <= 1024) ----
__global__ void __launch_bounds__(1024)
scan_top(int* __restrict__ bs, int nblk, int* __restrict__ rowStartN) {
    __shared__ int s[1024];
    int t = threadIdx.x;
    int x = (t < nblk) ? bs[t] : 0;
    s[t] = x;
    __syncthreads();
    for (int off = 1; off < 1024; off <<= 1) {
        int y = (t >= off) ? s[t - off] : 0;
        __syncthreads();
        s[t] += y;
        __syncthreads();
    }
    if (t < nblk) bs[t] = s[t] - x;            // exclusive
    if (t == 1023) *rowStartN = s[1023];       // total = E
}

// ---- K3c: per-block exclusive scan + block offset -> rowStart, cur ----
__global__ void __launch_bounds__(256)
scan_final(int* __restrict__ cur, const int* __restrict__ bs,
           int* __restrict__ rowStart, int n) {
    __shared__ int s[256];
    int t = threadIdx.x;
    int i = blockIdx.x * 256 + t;
    int x = (i < n) ? cur[i] : 0;
    s[t] = x;
    __syncthreads();
    for (int off = 1; off < 256; off <<= 1) {
        int y = (t >= off) ? s[t - off] : 0;
        __syncthreads();
        s[t] += y;
        __syncthreads();
    }
    int excl = s[t] - x + bs[blockIdx.x];
    if (i < n) { rowStart[i] = excl; cur[i] = excl; }
}

// ---- K4: scatter edges into CSR order ----
__global__ void scatter_kernel(const int* __restrict__ erows,
                               const int* __restrict__ ecols,
                               const float* __restrict__ evals,
                               int* __restrict__ cur, int2* __restrict__ pairs,
                               int n_edges) {
    int i = blockIdx.x * blockDim.x + threadIdx.x;
    int stride = gridDim.x * blockDim.x;
    for (int e = i; e < n_edges; e += stride) {
        int pos = atomicAdd(&cur[erows[e]], 1);
        pairs[pos] = make_int2(ecols[e], __float_as_int(evals[e]));
    }
}

// ---- K5: fused gather+aggregate+project+relu. One wave per row. ----
__global__ void __launch_bounds__(256)
fused_kernel(const float* __restrict__ feat, const int* __restrict__ rowStart,
             const int2* __restrict__ pairs, const float* __restrict__ W,
             float* __restrict__ out, int n_rows) {
    __shared__ float sW[D * D];   // 16 KB
    __shared__ float srow[4][D];

    for (int i = threadIdx.x; i < D * D; i += 256)
        sW[i] = W[i];

    const int w    = threadIdx.x >> 6;                       // wave slot 0..3
    const int lane = threadIdx.x & 63;
    const int row  = blockIdx.x * 4 + w;

    float acc = 0.0f;
    if (row < n_rows) {
        int s = rowStart[row];
        int e = rowStart[row + 1];
        int i = s;
        for (; i + 4 <= e; i += 4) {
            int2 p0 = pairs[i + 0], p1 = pairs[i + 1];
            int2 p2 = pairs[i + 2], p3 = pairs[i + 3];
            float f0 = feat[(size_t)p0.x * D + lane];
            float f1 = feat[(size_t)p1.x * D + lane];
            float f2 = feat[(size_t)p2.x * D + lane];
            float f3 = feat[(size_t)p3.x * D + lane];
            acc = fmaf(f0, __int_as_float(p0.y), acc);
            acc = fmaf(f1, __int_as_float(p1.y), acc);
            acc = fmaf(f2, __int_as_float(p2.y), acc);
            acc = fmaf(f3, __int_as_float(p3.y), acc);
        }
        for (; i < e; ++i) {
            int2 p = pairs[i];
            acc = fmaf(feat[(size_t)p.x * D + lane], __int_as_float(p.y), acc);
        }
    }
    srow[w][lane] = acc;
    __syncthreads();   // covers sW staging AND srow writes

    float o = 0.0f;
#pragma unroll
    for (int k = 0; k < D; ++k)
        o = fmaf(srow[w][k], sW[k * D + lane], o);

    if (row < n_rows)
        out[(size_t)row * D + lane] = fmaxf(o, 0.0f);
}

// ===========================================================================
// Fallback path (ws too small): round-1 atomic scatter into d_out + in-place
// projection.
// ===========================================================================
__global__ void agg_kernel(const float* __restrict__ feat,
                           const int* __restrict__ erows,
                           const int* __restrict__ ecols,
                           const float* __restrict__ evals,
                           float* __restrict__ agg, int n_edges) {
    int gid = blockIdx.x * blockDim.x + threadIdx.x;
    int group = gid >> 4, lane4 = gid & 15;
    int stride = (gridDim.x * blockDim.x) >> 4;
    for (int e = group; e < n_edges; e += stride) {
        int r = erows[e], c = ecols[e];
        float v = evals[e];
        const float4 f = *reinterpret_cast<const float4*>(feat + (size_t)c * D + lane4 * 4);
        float* dst = agg + (size_t)r * D + lane4 * 4;
        unsafeAtomicAdd(dst + 0, f.x * v);
        unsafeAtomicAdd(dst + 1, f.y * v);
        unsafeAtomicAdd(dst + 2, f.z * v);
        unsafeAtomicAdd(dst + 3, f.w * v);
    }
}

__global__ void __launch_bounds__(256)
proj_kernel(const float* __restrict__ agg, const float* __restrict__ W,
            float* __restrict__ out, int n_rows) {
    __shared__ float sW[D * D];
    __shared__ float srow[4][D];
    for (int i = threadIdx.x; i < D * D; i += 256) sW[i] = W[i];
    __syncthreads();
    const int rg = threadIdx.x >> 6, j = threadIdx.x & 63;
    for (int row0 = blockIdx.x * 4; row0 < n_rows; row0 += gridDim.x * 4) {
        int r = row0 + rg;
        float v = (r < n_rows) ? agg[(size_t)r * D + j] : 0.0f;
        srow[rg][j] = v;
        __syncthreads();
        float acc = 0.0f;
#pragma unroll
        for (int k = 0; k < D; ++k) acc = fmaf(srow[rg][k], sW[k * D + j], acc);
        if (r < n_rows) out[(size_t)r * D + j] = fmaxf(acc, 0.0f);
        __syncthreads();
    }
}

// ===========================================================================
extern "C" void kernel_launch(void* const* d_in, const int* in_sizes, int n_in,
                              void* d_out, int out_size, void* d_ws, size_t ws_size,
                              hipStream_t stream) {
    const float* feat  = (const float*)d_in[0];
    const int*   erows = (const int*)  d_in[1];
    const int*   ecols = (const int*)  d_in[2];
    const float* evals = (const float*)d_in[3];
    const float* W     = (const float*)d_in[4];
    float*       out   = (float*)d_out;

    const int n_edges = in_sizes[1];
    const int n_nodes = in_sizes[0] / D;
    const int nblk    = (n_nodes + 255) / 256;   // 391 for N=100k (<=1024)

    auto align256 = [](size_t x) { return (x + 255) & ~(size_t)255; };
    size_t off_rowStart = 0;
    size_t off_cur      = align256(off_rowStart + (size_t)(n_nodes + 1) * 4);
    size_t off_bs       = align256(off_cur + (size_t)n_nodes * 4);
    size_t off_pairs    = align256(off_bs + (size_t)nblk * 4);
    size_t ws_needed    = off_pairs + (size_t)n_edges * 8;

    if (ws_size >= ws_needed && nblk <= 1024) {
        char* ws = (char*)d_ws;
        int*  rowStart = (int*) (ws + off_rowStart);
        int*  cur      = (int*) (ws + off_cur);
        int*  bs       = (int*) (ws + off_bs);
        int2* pairs    = (int2*)(ws + off_pairs);

        hipMemsetAsync(cur, 0, (size_t)n_nodes * 4, stream);
        hist_kernel<<<2048, 256, 0, stream>>>(erows, cur, n_edges);
        scan_block_reduce<<<nblk, 256, 0, stream>>>(cur, bs, n_nodes);
        scan_top<<<1, 1024, 0, stream>>>(bs, nblk, rowStart + n_nodes);
        scan_final<<<nblk, 256, 0, stream>>>(cur, bs, rowStart, n_nodes);
        scatter_kernel<<<2048, 256, 0, stream>>>(erows, ecols, evals, cur, pairs, n_edges);
        fused_kernel<<<(n_nodes + 3) / 4, 256, 0, stream>>>(feat, rowStart, pairs, W, out, n_nodes);
    } else {
        // Fallback: atomic aggregation directly into out, in-place projection.
        hipMemsetAsync(out, 0, (size_t)n_nodes * D * 4, stream);
        agg_kernel<<<2048, 256, 0, stream>>>(feat, erows, ecols, evals, out, n_edges);
        proj_kernel<<<2048, 256, 0, stream>>>(out, W, out, n_nodes);
    }
}

// Round 5
// 267.644 us; speedup vs baseline: 5.5505x; 1.4839x over previous
//
#include <hip/hip_runtime.h>

#define D 64
#define OVF_CAP 262144

// ===========================================================================
// Tier-1/2 fast path: fixed-slot binning (no hist, no scan) + XCD-sliced
// scatter + shuffle-broadcast fused gather/project.
//
// ws layout (256B aligned):
//   cnt    : N int        — per-row degree counter (memset 0 each call)
//   ovfCnt : 1 int        — overflow edge count   (memset 0 each call)
//   ovf    : OVF_CAP int4 — overflow edges (r, c, val_bits, _)
//   pairs  : N*SLOTS int2 — (col, val_bits) for row r at pairs[r*SLOTS + k]
// ===========================================================================

template <int SLOTS>
__global__ void scatter_slot_kernel(const int* __restrict__ erows,
                                    const int* __restrict__ ecols,
                                    const float* __restrict__ evals,
                                    int* __restrict__ cnt,
                                    int2* __restrict__ pairs,
                                    int4* __restrict__ ovf,
                                    int* __restrict__ ovfCnt,
                                    int n_edges, int rows_per_slice) {
    // Row-sliced by presumed XCD (blockIdx % 8): all stores for a row come
    // from blocks in one slice -> one dirty L2 line copy instead of ~8.
    const int slice = blockIdx.x & 7;
    const int rlo   = slice * rows_per_slice;
    const int rhi   = rlo + rows_per_slice;
    const int sub   = blockIdx.x >> 3;
    const int t     = sub * blockDim.x + threadIdx.x;
    const int strid = (gridDim.x >> 3) * blockDim.x;

    for (int e = t; e < n_edges; e += strid) {
        int   r = erows[e];
        int   c = ecols[e];
        float v = evals[e];
        if (r >= rlo && r < rhi) {
            int pos = atomicAdd(&cnt[r], 1);
            if (pos < SLOTS) {
                pairs[(size_t)r * SLOTS + pos] = make_int2(c, __float_as_int(v));
            } else {
                int oi = atomicAdd(ovfCnt, 1);
                if (oi < OVF_CAP)
                    ovf[oi] = make_int4(r, c, __float_as_int(v), 0);
            }
        }
    }
}

// One wave per row. Lane l cooperatively loads pairs[row*SLOTS+l] (coalesced
// 512B), then the inner loop broadcasts (col,val) via __shfl; each lane owns
// feature column `lane`. Projection through LDS-staged W, fused ReLU when no
// overflow occurred.
template <int SLOTS>
__global__ void __launch_bounds__(256)
fused_slot_kernel(const float* __restrict__ feat, const int* __restrict__ cnt,
                  const int2* __restrict__ pairs, const float* __restrict__ W,
                  const int* __restrict__ ovfCnt, float* __restrict__ out,
                  int n_rows) {
    __shared__ float sW[D * D];   // 16 KB
    __shared__ float srow[4][D];

    for (int i = threadIdx.x; i < D * D; i += 256)
        sW[i] = W[i];

    const int  w      = threadIdx.x >> 6;
    const int  lane   = threadIdx.x & 63;
    const int  row    = blockIdx.x * 4 + w;
    const bool doRelu = (*ovfCnt == 0);

    float acc = 0.0f;
    if (row < n_rows) {
        int m = min(cnt[row], SLOTS);
        int px = 0, py = 0;
        if (lane < SLOTS) {
            int2 p = pairs[(size_t)row * SLOTS + lane];
            px = p.x; py = p.y;
        }
        int k = 0;
        for (; k + 4 <= m; k += 4) {
            int c0 = __shfl(px, k + 0), b0 = __shfl(py, k + 0);
            int c1 = __shfl(px, k + 1), b1 = __shfl(py, k + 1);
            int c2 = __shfl(px, k + 2), b2 = __shfl(py, k + 2);
            int c3 = __shfl(px, k + 3), b3 = __shfl(py, k + 3);
            float f0 = feat[(size_t)c0 * D + lane];
            float f1 = feat[(size_t)c1 * D + lane];
            float f2 = feat[(size_t)c2 * D + lane];
            float f3 = feat[(size_t)c3 * D + lane];
            acc = fmaf(f0, __int_as_float(b0), acc);
            acc = fmaf(f1, __int_as_float(b1), acc);
            acc = fmaf(f2, __int_as_float(b2), acc);
            acc = fmaf(f3, __int_as_float(b3), acc);
        }
        for (; k < m; ++k) {
            int c = __shfl(px, k), b = __shfl(py, k);
            acc = fmaf(feat[(size_t)c * D + lane], __int_as_float(b), acc);
        }
    }
    srow[w][lane] = acc;
    __syncthreads();   // covers sW staging AND srow writes

    float o = 0.0f;
#pragma unroll
    for (int kk = 0; kk < D; ++kk)
        o = fmaf(srow[w][kk], sW[kk * D + lane], o);

    if (row < n_rows)
        out[(size_t)row * D + lane] = doRelu ? fmaxf(o, 0.0f) : o;
}

// Overflow fix-up: per overflow edge, one wave computes v * (F[c] @ W) and
// atomically adds it into out[r]. No-op when ovfCnt == 0 (the expected case).
__global__ void __launch_bounds__(256)
ovf_kernel(const float* __restrict__ feat, const float* __restrict__ W,
           const int4* __restrict__ ovf, const int* __restrict__ ovfCnt,
           float* __restrict__ out) {
    int n = *ovfCnt;
    if (n > OVF_CAP) n = OVF_CAP;
    if (n == 0) return;
    const int lane = threadIdx.x & 63;
    const int wave = (blockIdx.x * blockDim.x + threadIdx.x) >> 6;
    const int nw   = (gridDim.x * blockDim.x) >> 6;
    for (int i = wave; i < n; i += nw) {
        int4  e = ovf[i];
        float v = __int_as_float(e.z);
        float f = feat[(size_t)e.y * D + lane];
        float acc = 0.0f;
#pragma unroll
        for (int k = 0; k < D; ++k)
            acc = fmaf(__shfl(f, k), W[k * D + lane], acc);
        unsafeAtomicAdd(&out[(size_t)e.x * D + lane], v * acc);
    }
}

// Deferred ReLU, only when overflow path ran (fused skipped ReLU then).
__global__ void relu_fix_kernel(float* __restrict__ out,
                                const int* __restrict__ ovfCnt, int n_elems) {
    if (*ovfCnt == 0) return;
    int i = blockIdx.x * blockDim.x + threadIdx.x;
    int stride = gridDim.x * blockDim.x;
    for (; i < n_elems; i += stride)
        out[i] = fmaxf(out[i], 0.0f);
}

// ===========================================================================
// Tier-3 fallback: round-3 CSR pipeline (hist + scan + scatter + fused).
// ===========================================================================
__global__ void hist_kernel(const int* __restrict__ erows, int* __restrict__ cur,
                            int n_edges) {
    int i = blockIdx.x * blockDim.x + threadIdx.x;
    int stride = gridDim.x * blockDim.x;
    for (int e = i; e < n_edges; e += stride)
        atomicAdd(&cur[erows[e]], 1);
}

__global__ void __launch_bounds__(256)
scan_block_reduce(const int* __restrict__ cnt, int* __restrict__ bs, int n) {
    __shared__ int s[256];
    int i = blockIdx.x * 256 + threadIdx.x;
    s[threadIdx.x] = (i < n) ? cnt[i] : 0;
    __syncthreads();
    for (int off = 128; off > 0; off >>= 1) {
        if (threadIdx.x < (unsigned)off) s[threadIdx.x] += s[threadIdx.x + off];
        __syncthreads();
    }
    if (threadIdx.x == 0) bs[blockIdx.x] = s[0];
}

__global__ void __launch_bounds__(1024)
scan_top(int* __restrict__ bs, int nblk, int* __restrict__ rowStartN) {
    __shared__ int s[1024];
    int t = threadIdx.x;
    int x = (t < nblk) ? bs[t] : 0;
    s[t] = x;
    __syncthreads();
    for (int off = 1; off < 1024; off <<= 1) {
        int y = (t >= off) ? s[t - off] : 0;
        __syncthreads();
        s[t] += y;
        __syncthreads();
    }
    if (t < nblk) bs[t] = s[t] - x;
    if (t == 1023) *rowStartN = s[1023];
}

__global__ void __launch_bounds__(256)
scan_final(int* __restrict__ cur, const int* __restrict__ bs,
           int* __restrict__ rowStart, int n) {
    __shared__ int s[256];
    int t = threadIdx.x;
    int i = blockIdx.x * 256 + t;
    int x = (i < n) ? cur[i] : 0;
    s[t] = x;
    __syncthreads();
    for (int off = 1; off < 256; off <<= 1) {
        int y = (t >= off) ? s[t - off] : 0;
        __syncthreads();
        s[t] += y;
        __syncthreads();
    }
    int excl = s[t] - x + bs[blockIdx.x];
    if (i < n) { rowStart[i] = excl; cur[i] = excl; }
}

__global__ void scatter_kernel(const int* __restrict__ erows,
                               const int* __restrict__ ecols,
                               const float* __restrict__ evals,
                               int* __restrict__ cur, int2* __restrict__ pairs,
                               int n_edges) {
    int i = blockIdx.x * blockDim.x + threadIdx.x;
    int stride = gridDim.x * blockDim.x;
    for (int e = i; e < n_edges; e += stride) {
        int pos = atomicAdd(&cur[erows[e]], 1);
        pairs[pos] = make_int2(ecols[e], __float_as_int(evals[e]));
    }
}

__global__ void __launch_bounds__(256)
fused_kernel(const float* __restrict__ feat, const int* __restrict__ rowStart,
             const int2* __restrict__ pairs, const float* __restrict__ W,
             float* __restrict__ out, int n_rows) {
    __shared__ float sW[D * D];
    __shared__ float srow[4][D];
    for (int i = threadIdx.x; i < D * D; i += 256) sW[i] = W[i];
    const int w = threadIdx.x >> 6, lane = threadIdx.x & 63;
    const int row = blockIdx.x * 4 + w;
    float acc = 0.0f;
    if (row < n_rows) {
        int s = rowStart[row], e = rowStart[row + 1], i = s;
        for (; i + 4 <= e; i += 4) {
            int2 p0 = pairs[i + 0], p1 = pairs[i + 1];
            int2 p2 = pairs[i + 2], p3 = pairs[i + 3];
            float f0 = feat[(size_t)p0.x * D + lane];
            float f1 = feat[(size_t)p1.x * D + lane];
            float f2 = feat[(size_t)p2.x * D + lane];
            float f3 = feat[(size_t)p3.x * D + lane];
            acc = fmaf(f0, __int_as_float(p0.y), acc);
            acc = fmaf(f1, __int_as_float(p1.y), acc);
            acc = fmaf(f2, __int_as_float(p2.y), acc);
            acc = fmaf(f3, __int_as_float(p3.y), acc);
        }
        for (; i < e; ++i) {
            int2 p = pairs[i];
            acc = fmaf(feat[(size_t)p.x * D + lane], __int_as_float(p.y), acc);
        }
    }
    srow[w][lane] = acc;
    __syncthreads();
    float o = 0.0f;
#pragma unroll
    for (int k = 0; k < D; ++k) o = fmaf(srow[w][k], sW[k * D + lane], o);
    if (row < n_rows) out[(size_t)row * D + lane] = fmaxf(o, 0.0f);
}

// ===========================================================================
// Tier-4 fallback: atomic aggregation directly into out + in-place proj.
// ===========================================================================
__global__ void agg_kernel(const float* __restrict__ feat,
                           const int* __restrict__ erows,
                           const int* __restrict__ ecols,
                           const float* __restrict__ evals,
                           float* __restrict__ agg, int n_edges) {
    int gid = blockIdx.x * blockDim.x + threadIdx.x;
    int group = gid >> 4, lane4 = gid & 15;
    int stride = (gridDim.x * blockDim.x) >> 4;
    for (int e = group; e < n_edges; e += stride) {
        int r = erows[e], c = ecols[e];
        float v = evals[e];
        const float4 f = *reinterpret_cast<const float4*>(feat + (size_t)c * D + lane4 * 4);
        float* dst = agg + (size_t)r * D + lane4 * 4;
        unsafeAtomicAdd(dst + 0, f.x * v);
        unsafeAtomicAdd(dst + 1, f.y * v);
        unsafeAtomicAdd(dst + 2, f.z * v);
        unsafeAtomicAdd(dst + 3, f.w * v);
    }
}

__global__ void __launch_bounds__(256)
proj_kernel(const float* __restrict__ agg, const float* __restrict__ W,
            float* __restrict__ out, int n_rows) {
    __shared__ float sW[D * D];
    __shared__ float srow[4][D];
    for (int i = threadIdx.x; i < D * D; i += 256) sW[i] = W[i];
    __syncthreads();
    const int rg = threadIdx.x >> 6, j = threadIdx.x & 63;
    for (int row0 = blockIdx.x * 4; row0 < n_rows; row0 += gridDim.x * 4) {
        int r = row0 + rg;
        float v = (r < n_rows) ? agg[(size_t)r * D + j] : 0.0f;
        srow[rg][j] = v;
        __syncthreads();
        float acc = 0.0f;
#pragma unroll
        for (int k = 0; k < D; ++k) acc = fmaf(srow[rg][k], sW[k * D + j], acc);
        if (r < n_rows) out[(size_t)r * D + j] = fmaxf(acc, 0.0f);
        __syncthreads();
    }
}

// ===========================================================================
extern "C" void kernel_launch(void* const* d_in, const int* in_sizes, int n_in,
                              void* d_out, int out_size, void* d_ws, size_t ws_size,
                              hipStream_t stream) {
    const float* feat  = (const float*)d_in[0];
    const int*   erows = (const int*)  d_in[1];
    const int*   ecols = (const int*)  d_in[2];
    const float* evals = (const float*)d_in[3];
    const float* W     = (const float*)d_in[4];
    float*       out   = (float*)d_out;

    const int n_edges = in_sizes[1];
    const int n_nodes = in_sizes[0] / D;

    auto align256 = [](size_t x) { return (x + 255) & ~(size_t)255; };

    // ---- slot-path layout ----
    size_t off_cnt    = 0;
    size_t off_ovfCnt = align256((size_t)n_nodes * 4);
    size_t off_ovf    = align256(off_ovfCnt + 4);
    size_t off_pairs  = align256(off_ovf + (size_t)OVF_CAP * 16);
    size_t need64     = off_pairs + (size_t)n_nodes * 64 * 8;
    size_t need32     = off_pairs + (size_t)n_nodes * 32 * 8;

    const int rows_per_slice = (n_nodes + 7) / 8;

    if (ws_size >= need64 || ws_size >= need32) {
        char* ws     = (char*)d_ws;
        int*  cnt    = (int*) (ws + off_cnt);
        int*  ovfCnt = (int*) (ws + off_ovfCnt);
        int4* ovf    = (int4*)(ws + off_ovf);
        int2* pairs  = (int2*)(ws + off_pairs);

        hipMemsetAsync(cnt, 0, (size_t)n_nodes * 4, stream);
        hipMemsetAsync(ovfCnt, 0, 4, stream);

        if (ws_size >= need64) {
            scatter_slot_kernel<64><<<2048, 256, 0, stream>>>(
                erows, ecols, evals, cnt, pairs, ovf, ovfCnt, n_edges, rows_per_slice);
            fused_slot_kernel<64><<<(n_nodes + 3) / 4, 256, 0, stream>>>(
                feat, cnt, pairs, W, ovfCnt, out, n_nodes);
        } else {
            scatter_slot_kernel<32><<<2048, 256, 0, stream>>>(
                erows, ecols, evals, cnt, pairs, ovf, ovfCnt, n_edges, rows_per_slice);
            fused_slot_kernel<32><<<(n_nodes + 3) / 4, 256, 0, stream>>>(
                feat, cnt, pairs, W, ovfCnt, out, n_nodes);
        }
        ovf_kernel<<<256, 256, 0, stream>>>(feat, W, ovf, ovfCnt, out);
        relu_fix_kernel<<<1024, 256, 0, stream>>>(out, ovfCnt, n_nodes * D);
        return;
    }

    // ---- CSR fallback ----
    const int nblk = (n_nodes + 255) / 256;
    size_t off_rowStart = 0;
    size_t off_cur      = align256(off_rowStart + (size_t)(n_nodes + 1) * 4);
    size_t off_bs       = align256(off_cur + (size_t)n_nodes * 4);
    size_t off_p        = align256(off_bs + (size_t)nblk * 4);
    size_t ws_needed    = off_p + (size_t)n_edges * 8;

    if (ws_size >= ws_needed && nblk <= 1024) {
        char* ws = (char*)d_ws;
        int*  rowStart = (int*) (ws + off_rowStart);
        int*  cur      = (int*) (ws + off_cur);
        int*  bs       = (int*) (ws + off_bs);
        int2* pairs    = (int2*)(ws + off_p);

        hipMemsetAsync(cur, 0, (size_t)n_nodes * 4, stream);
        hist_kernel<<<2048, 256, 0, stream>>>(erows, cur, n_edges);
        scan_block_reduce<<<nblk, 256, 0, stream>>>(cur, bs, n_nodes);
        scan_top<<<1, 1024, 0, stream>>>(bs, nblk, rowStart + n_nodes);
        scan_final<<<nblk, 256, 0, stream>>>(cur, bs, rowStart, n_nodes);
        scatter_kernel<<<2048, 256, 0, stream>>>(erows, ecols, evals, cur, pairs, n_edges);
        fused_kernel<<<(n_nodes + 3) / 4, 256, 0, stream>>>(feat, rowStart, pairs, W, out, n_nodes);
    } else {
        hipMemsetAsync(out, 0, (size_t)n_nodes * D * 4, stream);
        agg_kernel<<<2048, 256, 0, stream>>>(feat, erows, ecols, evals, out, n_edges);
        proj_kernel<<<2048, 256, 0, stream>>>(out, W, out, n_nodes);
    }
}